// Round 1
// baseline (699.799 us; speedup 1.0000x reference)
//
#include <hip/hip_runtime.h>

#define B_ 4
#define N_ 4096
#define ROWS (B_ * N_)            // 16384 rows per side
#define PTS_TOTAL (2 * ROWS)      // 32768 points total

__device__ __constant__ const float kLOG2E = 1.4426950408889634f;
#define LOG2E 1.4426950408889634f
#define LN2   0.6931471805599453f
#define EPS1  1e-4f               /* BLUR^P */
#define NEG_LOG2M (-12.0f)        /* -log2(4096) */

// ---- monotone float<->uint encode for atomicMax-based min/max ----
__device__ inline unsigned fenc(float f) {
  unsigned u = __float_as_uint(f);
  return (u & 0x80000000u) ? ~u : (u | 0x80000000u);
}
__device__ inline float fdec(unsigned u) {
  return (u & 0x80000000u) ? __uint_as_float(u & 0x7fffffffu)
                           : __uint_as_float(~u);
}
__device__ inline float fexp2(float x) { return __builtin_amdgcn_exp2f(x); }
__device__ inline float flog2(float x) { return __builtin_amdgcn_logf(x); }

// ---- init: zero the 13 encoded-max slots ----
__global__ void init_kernel(unsigned* enc) {
  if (threadIdx.x < 13) enc[threadIdx.x] = 0u;
}

// ---- global reductions: max coord-norm^2, per-dim max & min (flip-encoded) ----
__global__ __launch_bounds__(256) void reduce_kernel(
    const float* __restrict__ x, const float* __restrict__ y,
    unsigned* __restrict__ enc) {
  int idx = blockIdx.x * 256 + threadIdx.x;  // 0..32767, one point each
  const float* p = (idx < ROWS) ? (x + (size_t)idx * 6)
                                : (y + (size_t)(idx - ROWS) * 6);
  float d0 = p[0], d1 = p[1], d2 = p[2], d3 = p[3], d4 = p[4], d5 = p[5];
  float dd[6] = {d0, d1, d2, d3, d4, d5};
  unsigned e[13];
  e[0] = fenc(d0 * d0 + d1 * d1 + d2 * d2);
#pragma unroll
  for (int k = 0; k < 6; ++k) {
    e[1 + k] = fenc(dd[k]);      // per-dim max
    e[7 + k] = fenc(-dd[k]);     // per-dim min via max(-v)
  }
#pragma unroll
  for (int off = 32; off > 0; off >>= 1) {
#pragma unroll
    for (int k = 0; k < 13; ++k) {
      unsigned o = (unsigned)__shfl_xor((int)e[k], off);
      e[k] = e[k] > o ? e[k] : o;
    }
  }
  if ((threadIdx.x & 63) == 0) {
#pragma unroll
    for (int k = 0; k < 13; ++k) atomicMax(&enc[k], e[k]);
  }
}

// ---- pack points: u = (coords*s, 0.1*clip(col,0,1)), q = |u|^2 ; eps0 ; hh0 ----
__global__ __launch_bounds__(256) void pack_kernel(
    const float* __restrict__ x, const float* __restrict__ y,
    float4* __restrict__ XP, float4* __restrict__ YP,
    float* __restrict__ HHX0, float* __restrict__ HHY0,
    const unsigned* __restrict__ enc, float* __restrict__ sc) {
  int idx = blockIdx.x * 256 + threadIdx.x;  // 0..32767
  float maxnorm = sqrtf(fdec(enc[0]));
  float s = 1.0f / (maxnorm + 1e-6f);
  float eps0 = 0.0f;
#pragma unroll
  for (int k = 0; k < 6; ++k) {
    float mx = fdec(enc[1 + k]);
    float mn = -fdec(enc[7 + k]);
    float d = mx - mn;
    eps0 += d * d;                 // diameter^2 (P=2)
  }
  if (idx == 0) sc[13] = eps0;

  bool isx = idx < ROWS;
  int local = isx ? idx : idx - ROWS;
  const float* p = (isx ? x : y) + (size_t)local * 6;
  float c0 = p[0] * s, c1 = p[1] * s, c2 = p[2] * s;
  float l0 = 0.1f * fminf(fmaxf(p[3], 0.0f), 1.0f);
  float l1 = 0.1f * fminf(fmaxf(p[4], 0.0f), 1.0f);
  float l2 = 0.1f * fminf(fmaxf(p[5], 0.0f), 1.0f);
  float q = c0 * c0 + c1 * c1 + c2 * c2 + l0 * l0 + l1 * l1 + l2 * l2;
  float4* P = isx ? XP : YP;
  P[(size_t)local * 2]     = make_float4(c0, c1, c2, l0);
  P[(size_t)local * 2 + 1] = make_float4(l1, l2, q, 0.0f);
  // hh for the first two softmins: h = -ln(M), g = 0, eps = eps0  (base-2)
  float hh0 = NEG_LOG2M - q * (LOG2E / eps0);
  (isx ? HHX0 : HHY0)[local] = hh0;
}

// ---- fused softmin: out_i = q_i - eps*ln2*(m2 + log2 S),  optional 0.5-avg and
// ----                hh_out_i = -log2M + (out_i - q_i)/eps_next * log2e
__global__ __launch_bounds__(512) void softmin_kernel(
    const float4* __restrict__ rows, const float4* __restrict__ cols,
    const float* __restrict__ hh_in, const float* __restrict__ prev,
    float* __restrict__ out, float* __restrict__ hh_out,
    const float* __restrict__ sc, int eps_sel, int next_sel) {
  int lane = threadIdx.x & 63;
  int wave = threadIdx.x >> 6;
  int row = blockIdx.x * 64 + lane;   // 0..16383
  int b = row >> 12;                  // N_ = 4096
  int cb = b << 12;                   // column base for this batch

  float eps = eps_sel ? sc[13] : EPS1;
  float inv_eps = 1.0f / eps;

  float4 r0 = rows[(size_t)row * 2];
  float4 r1 = rows[(size_t)row * 2 + 1];
  float q = r1.z;
  float sc2 = 2.0f * inv_eps * LOG2E;
  float p0 = r0.x * sc2, p1 = r0.y * sc2, p2 = r0.z * sc2;
  float p3 = r0.w * sc2, p4 = r1.x * sc2, p5 = r1.y * sc2;

  float m = -3.0e38f, s = 0.0f;
  int j0 = cb + wave * (N_ / 8);
#pragma unroll 2
  for (int t = 0; t < N_ / 8; t += 8) {
    float v[8];
#pragma unroll
    for (int u = 0; u < 8; ++u) {
      int j = j0 + t + u;                       // wave-uniform -> s_load
      float4 c0 = cols[(size_t)j * 2];
      float4 c1 = cols[(size_t)j * 2 + 1];
      float acc = hh_in[j];
      acc = fmaf(p0, c0.x, acc);
      acc = fmaf(p1, c0.y, acc);
      acc = fmaf(p2, c0.z, acc);
      acc = fmaf(p3, c0.w, acc);
      acc = fmaf(p4, c1.x, acc);
      v[u] = fmaf(p5, c1.y, acc);
    }
    float lm = v[0];
#pragma unroll
    for (int u = 1; u < 8; ++u) lm = fmaxf(lm, v[u]);
    float ls = 0.0f;
#pragma unroll
    for (int u = 0; u < 8; ++u) ls += fexp2(v[u] - lm);
    float mn = fmaxf(m, lm);
    s = fmaf(s, fexp2(m - mn), ls * fexp2(lm - mn));
    m = mn;
  }

  __shared__ float msh[8][64];
  __shared__ float ssh[8][64];
  msh[wave][lane] = m;
  ssh[wave][lane] = s;
  __syncthreads();
  if (threadIdx.x < 64) {
    float M2 = msh[0][lane], S = ssh[0][lane];
#pragma unroll
    for (int w = 1; w < 8; ++w) {
      float mw = msh[w][lane], sw = ssh[w][lane];
      float mn = fmaxf(M2, mw);
      S = fmaf(S, fexp2(M2 - mn), sw * fexp2(mw - mn));
      M2 = mn;
    }
    float f_t = q - eps * LN2 * (M2 + flog2(S));
    float fo = prev ? 0.5f * (prev[row] + f_t) : f_t;
    out[row] = fo;
    if (hh_out) {
      float inv_next = next_sel ? (1.0f / sc[13]) : (1.0f / EPS1);
      hh_out[row] = NEG_LOG2M + (fo - q) * (inv_next * LOG2E);
    }
  }
}

// ---- final: 10/(B*N) * (sum f_new + sum g_new) ----
__global__ __launch_bounds__(256) void final_kernel(
    const float* __restrict__ FN, const float* __restrict__ GN,
    float* __restrict__ out) {
  float acc = 0.0f;
  for (int i = threadIdx.x; i < ROWS; i += 256) acc += FN[i] + GN[i];
  __shared__ float sh[256];
  sh[threadIdx.x] = acc;
  __syncthreads();
  for (int st = 128; st > 0; st >>= 1) {
    if (threadIdx.x < st) sh[threadIdx.x] += sh[threadIdx.x + st];
    __syncthreads();
  }
  if (threadIdx.x == 0) out[0] = sh[0] * (10.0f / (float)(B_ * N_));
}

extern "C" void kernel_launch(void* const* d_in, const int* in_sizes, int n_in,
                              void* d_out, int out_size, void* d_ws,
                              size_t ws_size, hipStream_t stream) {
  const float* x = (const float*)d_in[0];
  const float* y = (const float*)d_in[1];
  float* out = (float*)d_out;
  float* w = (float*)d_ws;
  unsigned* enc = (unsigned*)d_ws;
  float* sc = w;  // [0..12] encoded maxes, [13] eps0

  float* base = w + 16;
  float4* XP = (float4*)base;                    // 16384*8 floats
  float4* YP = (float4*)(base + 131072);         // 16384*8 floats
  float* HHX0 = base + 262144;
  float* HHY0 = HHX0 + ROWS;
  float* F1 = HHY0 + ROWS;
  float* G1 = F1 + ROWS;
  float* F2 = G1 + ROWS;
  float* G2 = F2 + ROWS;
  float* F3 = G2 + ROWS;
  float* G3 = F3 + ROWS;
  float* FN = G3 + ROWS;
  float* GN = FN + ROWS;
  float* HF1 = GN + ROWS;
  float* HG1 = HF1 + ROWS;
  float* HF2 = HG1 + ROWS;
  float* HG2 = HF2 + ROWS;
  float* HF3 = HG2 + ROWS;
  float* HG3 = HF3 + ROWS;

  init_kernel<<<1, 64, 0, stream>>>(enc);
  reduce_kernel<<<PTS_TOTAL / 256, 256, 0, stream>>>(x, y, enc);
  pack_kernel<<<PTS_TOTAL / 256, 256, 0, stream>>>(x, y, XP, YP, HHX0, HHY0,
                                                   enc, sc);
  dim3 g(ROWS / 64), blk(512);
  // 1: f1 = SM_xy(eps0, h=b_log)          -> also hh(F1) @ eps0 (for call 4)
  softmin_kernel<<<g, blk, 0, stream>>>(XP, YP, HHY0, nullptr, F1, HF1, sc, 1, 1);
  // 2: g1 = SM_yx(eps0, h=a_log)          -> hh(G1) @ eps0 (for call 3)
  softmin_kernel<<<g, blk, 0, stream>>>(YP, XP, HHX0, nullptr, G1, HG1, sc, 1, 1);
  // 3: f2 = 0.5(f1 + SM_xy(eps0, g1))     -> hh(F2) @ eps1 (for call 6)
  softmin_kernel<<<g, blk, 0, stream>>>(XP, YP, HG1, F1, F2, HF2, sc, 1, 0);
  // 4: g2 = 0.5(g1 + SM_yx(eps0, f1))     -> hh(G2) @ eps1 (for call 5)
  softmin_kernel<<<g, blk, 0, stream>>>(YP, XP, HF1, G1, G2, HG2, sc, 1, 0);
  // 5: f3 = 0.5(f2 + SM_xy(eps1, g2))     -> hh(F3) @ eps1 (for call 8)
  softmin_kernel<<<g, blk, 0, stream>>>(XP, YP, HG2, F2, F3, HF3, sc, 0, 0);
  // 6: g3 = 0.5(g2 + SM_yx(eps1, f2))     -> hh(G3) @ eps1 (for call 7)
  softmin_kernel<<<g, blk, 0, stream>>>(YP, XP, HF2, G2, G3, HG3, sc, 0, 0);
  // 7: f_new = SM_xy(eps1, g3)
  softmin_kernel<<<g, blk, 0, stream>>>(XP, YP, HG3, nullptr, FN, nullptr, sc, 0, 0);
  // 8: g_new = SM_yx(eps1, f3)
  softmin_kernel<<<g, blk, 0, stream>>>(YP, XP, HF3, nullptr, GN, nullptr, sc, 0, 0);
  final_kernel<<<1, 256, 0, stream>>>(FN, GN, out);
}

// Round 2
// 638.493 us; speedup vs baseline: 1.0960x; 1.0960x over previous
//
#include <hip/hip_runtime.h>

#define B_ 4
#define N_ 4096
#define ROWS (B_ * N_)            // 16384 rows per side
#define PTS_TOTAL (2 * ROWS)      // 32768 points total

#define LOG2E 1.4426950408889634f
#define LN2   0.6931471805599453f
#define EPS1  1e-4f               /* BLUR^P */
#define NEG_LOG2M (-12.0f)        /* -log2(4096) */
#define ENC_STRIDE 32             /* one slot per 128 B -> no same-line atomic pileup */

// ---- monotone float<->uint encode for atomicMax-based min/max ----
__device__ inline unsigned fenc(float f) {
  unsigned u = __float_as_uint(f);
  return (u & 0x80000000u) ? ~u : (u | 0x80000000u);
}
__device__ inline float fdec(unsigned u) {
  return (u & 0x80000000u) ? __uint_as_float(u & 0x7fffffffu)
                           : __uint_as_float(~u);
}
__device__ inline float fexp2(float x) { return __builtin_amdgcn_exp2f(x); }
__device__ inline float flog2(float x) { return __builtin_amdgcn_logf(x); }

// ---- init: zero the 13 encoded-max slots (strided) ----
__global__ void init_kernel(unsigned* enc) {
  if (threadIdx.x < 13) enc[threadIdx.x * ENC_STRIDE] = 0u;
}

// ---- reduce: max coord-norm^2, per-dim max & min. 32 blocks, 4 pts/thread,
// ---- LDS block-merge, 13 parallel atomics per block to strided slots.
__global__ __launch_bounds__(256) void reduce_kernel(
    const float* __restrict__ x, const float* __restrict__ y,
    unsigned* __restrict__ enc) {
  int t = blockIdx.x * 256 + threadIdx.x;     // 0..8191, 4 points each
  bool isx = t < (ROWS / 4);
  int local = (isx ? t : t - ROWS / 4) * 4;   // first of 4 points
  const float* p = (isx ? x : y) + (size_t)local * 6;
  unsigned e[13];
#pragma unroll
  for (int k = 0; k < 13; ++k) e[k] = 0u;
#pragma unroll
  for (int pt = 0; pt < 4; ++pt) {
    float d[6];
#pragma unroll
    for (int k = 0; k < 6; ++k) d[k] = p[pt * 6 + k];
    unsigned n2 = fenc(d[0] * d[0] + d[1] * d[1] + d[2] * d[2]);
    e[0] = e[0] > n2 ? e[0] : n2;
#pragma unroll
    for (int k = 0; k < 6; ++k) {
      unsigned a = fenc(d[k]), b = fenc(-d[k]);
      e[1 + k] = e[1 + k] > a ? e[1 + k] : a;
      e[7 + k] = e[7 + k] > b ? e[7 + k] : b;
    }
  }
#pragma unroll
  for (int off = 32; off > 0; off >>= 1) {
#pragma unroll
    for (int k = 0; k < 13; ++k) {
      unsigned o = (unsigned)__shfl_xor((int)e[k], off);
      e[k] = e[k] > o ? e[k] : o;
    }
  }
  __shared__ unsigned sh[4][13];
  int wave = threadIdx.x >> 6, lane = threadIdx.x & 63;
  if (lane == 0) {
#pragma unroll
    for (int k = 0; k < 13; ++k) sh[wave][k] = e[k];
  }
  __syncthreads();
  if (threadIdx.x < 13) {
    unsigned v = sh[0][threadIdx.x];
#pragma unroll
    for (int w = 1; w < 4; ++w) v = v > sh[w][threadIdx.x] ? v : sh[w][threadIdx.x];
    atomicMax(&enc[threadIdx.x * ENC_STRIDE], v);
  }
}

// ---- pack: u=(coords*s, 0.1*clip(col)), q=|u|^2 ; eps0 ; hh0 ----
__global__ __launch_bounds__(256) void pack_kernel(
    const float* __restrict__ x, const float* __restrict__ y,
    float4* __restrict__ XP, float4* __restrict__ YP,
    float* __restrict__ HHX0, float* __restrict__ HHY0,
    const unsigned* __restrict__ enc, float* __restrict__ sc) {
  int idx = blockIdx.x * 256 + threadIdx.x;  // 0..32767
  float maxnorm = sqrtf(fdec(enc[0]));
  float s = 1.0f / (maxnorm + 1e-6f);
  float eps0 = 0.0f;
#pragma unroll
  for (int k = 0; k < 6; ++k) {
    float mx = fdec(enc[(1 + k) * ENC_STRIDE]);
    float mn = -fdec(enc[(7 + k) * ENC_STRIDE]);
    float d = mx - mn;
    eps0 += d * d;                 // diameter^2 (P=2)
  }
  if (idx == 0) sc[0] = eps0;

  bool isx = idx < ROWS;
  int local = isx ? idx : idx - ROWS;
  const float* p = (isx ? x : y) + (size_t)local * 6;
  float c0 = p[0] * s, c1 = p[1] * s, c2 = p[2] * s;
  float l0 = 0.1f * fminf(fmaxf(p[3], 0.0f), 1.0f);
  float l1 = 0.1f * fminf(fmaxf(p[4], 0.0f), 1.0f);
  float l2 = 0.1f * fminf(fmaxf(p[5], 0.0f), 1.0f);
  float q = c0 * c0 + c1 * c1 + c2 * c2 + l0 * l0 + l1 * l1 + l2 * l2;
  float4* P = isx ? XP : YP;
  P[(size_t)local * 2]     = make_float4(c0, c1, c2, l0);
  P[(size_t)local * 2 + 1] = make_float4(l1, l2, q, 0.0f);
  float hh0 = NEG_LOG2M - q * (LOG2E / eps0);   // h=-lnM, g=0, eps=eps0
  (isx ? HHX0 : HHY0)[local] = hh0;
}

// ---- fused softmin PAIR: blocks [0,4096) do xy-direction, [4096,8192) yx.
// ---- one wave per row, lanes strided over columns, butterfly-merge (m,s).
__global__ __launch_bounds__(256, 6) void softmin_pair_kernel(
    const float4* __restrict__ XP, const float4* __restrict__ YP,
    const float* __restrict__ hhY, const float* __restrict__ hhX,
    const float* __restrict__ prevF, const float* __restrict__ prevG,
    float* __restrict__ outF, float* __restrict__ outG,
    float* __restrict__ hhFo, float* __restrict__ hhGo,
    const float* __restrict__ sc, int eps_sel, int next_sel) {
  int wave = threadIdx.x >> 6, lane = threadIdx.x & 63;
  int dir = blockIdx.x >> 12;                       // 0: xy, 1: yx
  int row = ((blockIdx.x & 4095) << 2) + wave;      // 0..16383
  const float4* rows = dir ? YP : XP;
  const float4* cols = dir ? XP : YP;
  const float* hh    = dir ? hhX : hhY;
  const float* prev  = dir ? prevG : prevF;
  float* out = dir ? outG : outF;
  float* hho = dir ? hhGo : hhFo;

  float eps = eps_sel ? sc[0] : EPS1;
  float inv_eps = 1.0f / eps;

  float4 r0 = rows[(size_t)row * 2];
  float4 r1 = rows[(size_t)row * 2 + 1];
  float q = r1.z;
  float sc2 = 2.0f * inv_eps * LOG2E;
  float p0 = r0.x * sc2, p1 = r0.y * sc2, p2 = r0.z * sc2;
  float p3 = r0.w * sc2, p4 = r1.x * sc2, p5 = r1.y * sc2;

  int cb = (row >> 12) << 12;     // column base for this batch
  int jb = cb + lane;
  const float4* __restrict__ cp = cols + ((size_t)jb << 1);
  const float* __restrict__ hp = hh + jb;

  float m = -3.0e38f, s = 0.0f;
#pragma unroll 2
  for (int k0 = 0; k0 < 64; k0 += 4) {
    float v[4];
#pragma unroll
    for (int u = 0; u < 4; ++u) {
      int off = (k0 + u) << 6;                      // column step = 64
      float4 c0 = cp[(size_t)off * 2];
      float4 c1 = cp[(size_t)off * 2 + 1];
      float acc = hp[off];
      acc = fmaf(p0, c0.x, acc);
      acc = fmaf(p1, c0.y, acc);
      acc = fmaf(p2, c0.z, acc);
      acc = fmaf(p3, c0.w, acc);
      acc = fmaf(p4, c1.x, acc);
      v[u] = fmaf(p5, c1.y, acc);
    }
    float lm = fmaxf(fmaxf(v[0], v[1]), fmaxf(v[2], v[3]));
    float ls = fexp2(v[0] - lm) + fexp2(v[1] - lm) +
               fexp2(v[2] - lm) + fexp2(v[3] - lm);
    float mn = fmaxf(m, lm);
    s = fmaf(s, fexp2(m - mn), ls * fexp2(lm - mn));
    m = mn;
  }

  // 64-lane butterfly merge of (m, s)
#pragma unroll
  for (int off = 32; off > 0; off >>= 1) {
    float mo = __shfl_xor(m, off);
    float so = __shfl_xor(s, off);
    float mn = fmaxf(m, mo);
    s = fmaf(s, fexp2(m - mn), so * fexp2(mo - mn));
    m = mn;
  }

  if (lane == 0) {
    float f_t = q - eps * LN2 * (m + flog2(s));
    float fo = prev ? 0.5f * (prev[row] + f_t) : f_t;
    out[row] = fo;
    if (hho) {
      float inv_next = next_sel ? (1.0f / sc[0]) : (1.0f / EPS1);
      hho[row] = NEG_LOG2M + (fo - q) * (inv_next * LOG2E);
    }
  }
}

// ---- final: 10/(B*N) * (sum f_new + sum g_new) ----
__global__ __launch_bounds__(256) void final_kernel(
    const float* __restrict__ FN, const float* __restrict__ GN,
    float* __restrict__ out) {
  float acc = 0.0f;
  for (int i = threadIdx.x; i < ROWS; i += 256) acc += FN[i] + GN[i];
  __shared__ float sh[256];
  sh[threadIdx.x] = acc;
  __syncthreads();
  for (int st = 128; st > 0; st >>= 1) {
    if (threadIdx.x < st) sh[threadIdx.x] += sh[threadIdx.x + st];
    __syncthreads();
  }
  if (threadIdx.x == 0) out[0] = sh[0] * (10.0f / (float)(B_ * N_));
}

extern "C" void kernel_launch(void* const* d_in, const int* in_sizes, int n_in,
                              void* d_out, int out_size, void* d_ws,
                              size_t ws_size, hipStream_t stream) {
  const float* x = (const float*)d_in[0];
  const float* y = (const float*)d_in[1];
  float* out = (float*)d_out;
  float* w = (float*)d_ws;
  unsigned* enc = (unsigned*)d_ws;        // 13 slots at stride 32 (words 0..415)
  float* sc = w + 448;                    // sc[0] = eps0

  float* base = w + 512;
  float4* XP = (float4*)base;                    // 16384*8 floats
  float4* YP = (float4*)(base + 131072);
  float* HHX0 = base + 262144;
  float* HHY0 = HHX0 + ROWS;
  float* F1 = HHY0 + ROWS;
  float* G1 = F1 + ROWS;
  float* F2 = G1 + ROWS;
  float* G2 = F2 + ROWS;
  float* F3 = G2 + ROWS;
  float* G3 = F3 + ROWS;
  float* FN = G3 + ROWS;
  float* GN = FN + ROWS;
  float* HF1 = GN + ROWS;
  float* HG1 = HF1 + ROWS;
  float* HF2 = HG1 + ROWS;
  float* HG2 = HF2 + ROWS;
  float* HF3 = HG2 + ROWS;
  float* HG3 = HF3 + ROWS;

  init_kernel<<<1, 64, 0, stream>>>(enc);
  reduce_kernel<<<32, 256, 0, stream>>>(x, y, enc);
  pack_kernel<<<PTS_TOTAL / 256, 256, 0, stream>>>(x, y, XP, YP, HHX0, HHY0,
                                                   enc, sc);
  dim3 g(8192), blk(256);
  // pair 1: f1 = SM_xy(eps0, hh=HHY0); g1 = SM_yx(eps0, hh=HHX0)
  softmin_pair_kernel<<<g, blk, 0, stream>>>(XP, YP, HHY0, HHX0, nullptr,
                                             nullptr, F1, G1, HF1, HG1, sc, 1, 1);
  // pair 2: f2 = .5(f1+SM_xy(eps0,HG1)); g2 = .5(g1+SM_yx(eps0,HF1)); next eps1
  softmin_pair_kernel<<<g, blk, 0, stream>>>(XP, YP, HG1, HF1, F1, G1, F2, G2,
                                             HF2, HG2, sc, 1, 0);
  // pair 3: f3 = .5(f2+SM_xy(eps1,HG2)); g3 = .5(g2+SM_yx(eps1,HF2))
  softmin_pair_kernel<<<g, blk, 0, stream>>>(XP, YP, HG2, HF2, F2, G2, F3, G3,
                                             HF3, HG3, sc, 0, 0);
  // pair 4: f_new = SM_xy(eps1,HG3); g_new = SM_yx(eps1,HF3)
  softmin_pair_kernel<<<g, blk, 0, stream>>>(XP, YP, HG3, HF3, nullptr, nullptr,
                                             FN, GN, nullptr, nullptr, sc, 0, 0);
  final_kernel<<<1, 256, 0, stream>>>(FN, GN, out);
}

// Round 3
// 275.402 us; speedup vs baseline: 2.5410x; 2.3184x over previous
//
#include <hip/hip_runtime.h>

#define B_ 4
#define N_ 4096
#define ROWS (B_ * N_)            // 16384 rows per side
#define PTS_TOTAL (2 * ROWS)      // 32768 points total

#define LOG2E 1.4426950408889634f
#define LN2   0.6931471805599453f
#define EPS1  1e-4f               /* BLUR^P */
#define NEG_LOG2M (-12.0f)        /* -log2(4096) */
#define ENC_STRIDE 32             /* one slot per 128 B -> no same-line atomic pileup */

typedef float f2 __attribute__((ext_vector_type(2)));

// ---- monotone float<->uint encode for atomicMax-based min/max ----
__device__ inline unsigned fenc(float f) {
  unsigned u = __float_as_uint(f);
  return (u & 0x80000000u) ? ~u : (u | 0x80000000u);
}
__device__ inline float fdec(unsigned u) {
  return (u & 0x80000000u) ? __uint_as_float(u & 0x7fffffffu)
                           : __uint_as_float(~u);
}
__device__ inline float fexp2(float x) { return __builtin_amdgcn_exp2f(x); }
__device__ inline float flog2(float x) { return __builtin_amdgcn_logf(x); }

// ---- init: zero the 13 encoded-max slots (strided) ----
__global__ void init_kernel(unsigned* enc) {
  if (threadIdx.x < 13) enc[threadIdx.x * ENC_STRIDE] = 0u;
}

// ---- reduce: max coord-norm^2, per-dim max & min ----
__global__ __launch_bounds__(256) void reduce_kernel(
    const float* __restrict__ x, const float* __restrict__ y,
    unsigned* __restrict__ enc) {
  int t = blockIdx.x * 256 + threadIdx.x;     // 0..8191, 4 points each
  bool isx = t < (ROWS / 4);
  int local = (isx ? t : t - ROWS / 4) * 4;
  const float* p = (isx ? x : y) + (size_t)local * 6;
  unsigned e[13];
#pragma unroll
  for (int k = 0; k < 13; ++k) e[k] = 0u;
#pragma unroll
  for (int pt = 0; pt < 4; ++pt) {
    float d[6];
#pragma unroll
    for (int k = 0; k < 6; ++k) d[k] = p[pt * 6 + k];
    unsigned n2 = fenc(d[0] * d[0] + d[1] * d[1] + d[2] * d[2]);
    e[0] = e[0] > n2 ? e[0] : n2;
#pragma unroll
    for (int k = 0; k < 6; ++k) {
      unsigned a = fenc(d[k]), b = fenc(-d[k]);
      e[1 + k] = e[1 + k] > a ? e[1 + k] : a;
      e[7 + k] = e[7 + k] > b ? e[7 + k] : b;
    }
  }
#pragma unroll
  for (int off = 32; off > 0; off >>= 1) {
#pragma unroll
    for (int k = 0; k < 13; ++k) {
      unsigned o = (unsigned)__shfl_xor((int)e[k], off);
      e[k] = e[k] > o ? e[k] : o;
    }
  }
  __shared__ unsigned sh[4][13];
  int wave = threadIdx.x >> 6, lane = threadIdx.x & 63;
  if (lane == 0) {
#pragma unroll
    for (int k = 0; k < 13; ++k) sh[wave][k] = e[k];
  }
  __syncthreads();
  if (threadIdx.x < 13) {
    unsigned v = sh[0][threadIdx.x];
#pragma unroll
    for (int w = 1; w < 4; ++w) v = v > sh[w][threadIdx.x] ? v : sh[w][threadIdx.x];
    atomicMax(&enc[threadIdx.x * ENC_STRIDE], v);
  }
}

// ---- pack: u=(coords*s, 0.1*clip(col)), q=|u|^2 ; eps0 ; hh0 ----
__global__ __launch_bounds__(256) void pack_kernel(
    const float* __restrict__ x, const float* __restrict__ y,
    float4* __restrict__ XP, float4* __restrict__ YP,
    float* __restrict__ HHX0, float* __restrict__ HHY0,
    const unsigned* __restrict__ enc, float* __restrict__ sc) {
  int idx = blockIdx.x * 256 + threadIdx.x;  // 0..32767
  float maxnorm = sqrtf(fdec(enc[0]));
  float s = 1.0f / (maxnorm + 1e-6f);
  float eps0 = 0.0f;
#pragma unroll
  for (int k = 0; k < 6; ++k) {
    float mx = fdec(enc[(1 + k) * ENC_STRIDE]);
    float mn = -fdec(enc[(7 + k) * ENC_STRIDE]);
    float d = mx - mn;
    eps0 += d * d;                 // diameter^2 (P=2)
  }
  if (idx == 0) sc[0] = eps0;

  bool isx = idx < ROWS;
  int local = isx ? idx : idx - ROWS;
  const float* p = (isx ? x : y) + (size_t)local * 6;
  float c0 = p[0] * s, c1 = p[1] * s, c2 = p[2] * s;
  float l0 = 0.1f * fminf(fmaxf(p[3], 0.0f), 1.0f);
  float l1 = 0.1f * fminf(fmaxf(p[4], 0.0f), 1.0f);
  float l2 = 0.1f * fminf(fmaxf(p[5], 0.0f), 1.0f);
  float q = c0 * c0 + c1 * c1 + c2 * c2 + l0 * l0 + l1 * l1 + l2 * l2;
  float4* P = isx ? XP : YP;
  P[(size_t)local * 2]     = make_float4(c0, c1, c2, l0);
  P[(size_t)local * 2 + 1] = make_float4(l1, l2, q, 0.0f);
  float hh0 = NEG_LOG2M - q * (LOG2E / eps0);   // h=-lnM, g=0, eps=eps0
  (isx ? HHX0 : HHY0)[local] = hh0;
}

// ---- fused softmin PAIR, 8 rows per wave (register reuse of column data).
// ---- blocks [0,512) xy-direction, [512,1024) yx. 4 waves/block, no LDS.
__global__ __launch_bounds__(256) void softmin_pair_kernel(
    const float4* __restrict__ XP, const float4* __restrict__ YP,
    const float* __restrict__ hhY, const float* __restrict__ hhX,
    const float* __restrict__ prevF, const float* __restrict__ prevG,
    float* __restrict__ outF, float* __restrict__ outG,
    float* __restrict__ hhFo, float* __restrict__ hhGo,
    const float* __restrict__ sc, int eps_sel, int next_sel) {
  int wave = threadIdx.x >> 6, lane = threadIdx.x & 63;
  int dir = blockIdx.x >> 9;                    // 0: xy, 1: yx
  int gw = ((blockIdx.x & 511) << 2) | wave;    // 0..2047
  int r0 = gw << 3;                             // first of 8 rows
  const float4* rows = dir ? YP : XP;
  const float4* cols = dir ? XP : YP;
  const float* hh    = dir ? hhX : hhY;
  const float* prev  = dir ? prevG : prevF;
  float* out = dir ? outG : outF;
  float* hho = dir ? hhGo : hhFo;

  float eps = eps_sel ? sc[0] : EPS1;
  float sc2 = 2.0f * LOG2E / eps;

  f2 P01[8], P23[8], P45[8];
  float Q[8];
#pragma unroll
  for (int r = 0; r < 8; ++r) {
    float4 a = rows[(size_t)(r0 + r) * 2];
    float4 b = rows[(size_t)(r0 + r) * 2 + 1];
    P01[r] = f2{a.x * sc2, a.y * sc2};
    P23[r] = f2{a.z * sc2, a.w * sc2};
    P45[r] = f2{b.x * sc2, b.y * sc2};
    Q[r] = b.z;
  }

  int cb = (r0 >> 12) << 12;    // batch column base (8 rows never cross batch)
  const float4* __restrict__ cp = cols + ((size_t)(cb + lane) << 1);
  const float* __restrict__ hp = hh + cb + lane;

  float m[8], s[8];
#pragma unroll
  for (int r = 0; r < 8; ++r) { m[r] = -3.0e38f; s[r] = 0.0f; }

  for (int g = 0; g < 16; ++g) {
    f2 C01[4], C23[4], C45[4];
    float H[4];
#pragma unroll
    for (int u = 0; u < 4; ++u) {
      int off = ((g << 2) | u) << 6;            // column step = 64 lanes
      float4 c0 = cp[(size_t)off << 1];
      float4 c1 = cp[((size_t)off << 1) + 1];
      C01[u] = f2{c0.x, c0.y};
      C23[u] = f2{c0.z, c0.w};
      C45[u] = f2{c1.x, c1.y};
      H[u] = hp[off];
    }
#pragma unroll
    for (int r = 0; r < 8; ++r) {
      float v[4];
#pragma unroll
      for (int u = 0; u < 4; ++u) {
        f2 acc = f2{H[u], 0.0f};
        acc = __builtin_elementwise_fma(P01[r], C01[u], acc);
        acc = __builtin_elementwise_fma(P23[r], C23[u], acc);
        acc = __builtin_elementwise_fma(P45[r], C45[u], acc);
        v[u] = acc.x + acc.y;
      }
      float gm = fmaxf(fmaxf(v[0], v[1]), fmaxf(v[2], v[3]));
      float ls = fexp2(v[0] - gm) + fexp2(v[1] - gm) +
                 fexp2(v[2] - gm) + fexp2(v[3] - gm);
      float mn = fmaxf(m[r], gm);
      s[r] = fmaf(s[r], fexp2(m[r] - mn), ls * fexp2(gm - mn));
      m[r] = mn;
    }
  }

  // 64-lane butterfly merge of (m, s) per row
#pragma unroll
  for (int off = 32; off > 0; off >>= 1) {
#pragma unroll
    for (int r = 0; r < 8; ++r) {
      float mo = __shfl_xor(m[r], off);
      float so = __shfl_xor(s[r], off);
      float mn = fmaxf(m[r], mo);
      s[r] = fmaf(s[r], fexp2(m[r] - mn), so * fexp2(mo - mn));
      m[r] = mn;
    }
  }

  if (lane == 0) {
    float inv_next = next_sel ? (1.0f / sc[0]) : (1.0f / EPS1);
#pragma unroll
    for (int r = 0; r < 8; ++r) {
      int row = r0 + r;
      float f_t = Q[r] - eps * LN2 * (m[r] + flog2(s[r]));
      float fo = prev ? 0.5f * (prev[row] + f_t) : f_t;
      out[row] = fo;
      if (hho) hho[row] = NEG_LOG2M + (fo - Q[r]) * (inv_next * LOG2E);
    }
  }
}

// ---- final: 10/(B*N) * (sum f_new + sum g_new) ----
__global__ __launch_bounds__(256) void final_kernel(
    const float* __restrict__ FN, const float* __restrict__ GN,
    float* __restrict__ out) {
  float acc = 0.0f;
  for (int i = threadIdx.x; i < ROWS; i += 256) acc += FN[i] + GN[i];
  __shared__ float sh[256];
  sh[threadIdx.x] = acc;
  __syncthreads();
  for (int st = 128; st > 0; st >>= 1) {
    if (threadIdx.x < st) sh[threadIdx.x] += sh[threadIdx.x + st];
    __syncthreads();
  }
  if (threadIdx.x == 0) out[0] = sh[0] * (10.0f / (float)(B_ * N_));
}

extern "C" void kernel_launch(void* const* d_in, const int* in_sizes, int n_in,
                              void* d_out, int out_size, void* d_ws,
                              size_t ws_size, hipStream_t stream) {
  const float* x = (const float*)d_in[0];
  const float* y = (const float*)d_in[1];
  float* out = (float*)d_out;
  float* w = (float*)d_ws;
  unsigned* enc = (unsigned*)d_ws;        // 13 slots at stride 32
  float* sc = w + 448;                    // sc[0] = eps0

  float* base = w + 512;
  float4* XP = (float4*)base;                    // 16384*8 floats
  float4* YP = (float4*)(base + 131072);
  float* HHX0 = base + 262144;
  float* HHY0 = HHX0 + ROWS;
  float* F1 = HHY0 + ROWS;
  float* G1 = F1 + ROWS;
  float* F2 = G1 + ROWS;
  float* G2 = F2 + ROWS;
  float* F3 = G2 + ROWS;
  float* G3 = F3 + ROWS;
  float* FN = G3 + ROWS;
  float* GN = FN + ROWS;
  float* HF1 = GN + ROWS;
  float* HG1 = HF1 + ROWS;
  float* HF2 = HG1 + ROWS;
  float* HG2 = HF2 + ROWS;
  float* HF3 = HG2 + ROWS;
  float* HG3 = HF3 + ROWS;

  init_kernel<<<1, 64, 0, stream>>>(enc);
  reduce_kernel<<<32, 256, 0, stream>>>(x, y, enc);
  pack_kernel<<<PTS_TOTAL / 256, 256, 0, stream>>>(x, y, XP, YP, HHX0, HHY0,
                                                   enc, sc);
  dim3 g(1024), blk(256);
  softmin_pair_kernel<<<g, blk, 0, stream>>>(XP, YP, HHY0, HHX0, nullptr,
                                             nullptr, F1, G1, HF1, HG1, sc, 1, 1);
  softmin_pair_kernel<<<g, blk, 0, stream>>>(XP, YP, HG1, HF1, F1, G1, F2, G2,
                                             HF2, HG2, sc, 1, 0);
  softmin_pair_kernel<<<g, blk, 0, stream>>>(XP, YP, HG2, HF2, F2, G2, F3, G3,
                                             HF3, HG3, sc, 0, 0);
  softmin_pair_kernel<<<g, blk, 0, stream>>>(XP, YP, HG3, HF3, nullptr, nullptr,
                                             FN, GN, nullptr, nullptr, sc, 0, 0);
  final_kernel<<<1, 256, 0, stream>>>(FN, GN, out);
}